// Round 3
// baseline (288.459 us; speedup 1.0000x reference)
//
#include <hip/hip_runtime.h>
#include <hip/hip_bf16.h>

// CosineLoss: out = mean_i( 1 - dot(a_i,b_i) / (||a_i||*||b_i||) )
// inputs: d_in[0]=cxr (N,D) f32, d_in[1]=ehr (N,D) f32; N=16384, D=2048.
//
// R2 lesson: wave-per-row was latency-bound (1.3 TB/s): 16 KB per wave, then
// a ~2-3k cycle serial shuffle/barrier/retire tail -> waves mostly idle on
// the memory pipe. Now: persistent grid (4096 waves = 16/CU, one round),
// 4 rows per wave (64 KB streamed), double-buffered loads so 8 x 16B loads
// stay in flight per lane, reduce tail paid once per wave.

#define ROWS 16384
#define COLS 2048
#define BLOCK 256
#define GRID 1024                 // 4 blocks/CU * 256 CU; 4096 waves total
#define RPW 4                     // rows per wave; 1024*4*4 = 16384 rows
#define NVEC (COLS / 4)           // 512 float4 per row
#define KSTEPS (NVEC / 64)        // 8 k-steps per row per lane

__global__ __launch_bounds__(BLOCK, 4) void cosine_partial_kernel(
    const float4* __restrict__ cxr,
    const float4* __restrict__ ehr,
    float* __restrict__ partial) {
    const int wave = threadIdx.x >> 6;
    const int lane = threadIdx.x & 63;
    const int wid  = blockIdx.x * (BLOCK / 64) + wave;   // 0..4095
    const int row0 = wid * RPW;

    const float4* __restrict__ a0 = cxr + (size_t)row0 * NVEC + lane;
    const float4* __restrict__ b0 = ehr + (size_t)row0 * NVEC + lane;

    float dot[RPW], aa[RPW], bb[RPW];
    #pragma unroll
    for (int r = 0; r < RPW; ++r) { dot[r] = 0.f; aa[r] = 0.f; bb[r] = 0.f; }

    // Double-buffered: while FMAs consume buffer `cur`, the 8 loads for the
    // next k-step are in flight into buffer `nxt`.
    float4 xb[2][RPW], yb[2][RPW];
    #pragma unroll
    for (int r = 0; r < RPW; ++r) {
        xb[0][r] = a0[r * NVEC];
        yb[0][r] = b0[r * NVEC];
    }

    #pragma unroll
    for (int k = 0; k < KSTEPS; ++k) {
        const int cur = k & 1;
        const int nxt = cur ^ 1;
        if (k + 1 < KSTEPS) {
            #pragma unroll
            for (int r = 0; r < RPW; ++r) {
                xb[nxt][r] = a0[r * NVEC + (k + 1) * 64];
                yb[nxt][r] = b0[r * NVEC + (k + 1) * 64];
            }
        }
        #pragma unroll
        for (int r = 0; r < RPW; ++r) {
            float4 x = xb[cur][r];
            float4 y = yb[cur][r];
            dot[r] += x.x * y.x + x.y * y.y + x.z * y.z + x.w * y.w;
            aa[r]  += x.x * x.x + x.y * x.y + x.z * x.z + x.w * x.w;
            bb[r]  += y.x * y.x + y.y * y.y + y.z * y.z + y.w * y.w;
        }
    }

    // 12 independent 6-step shuffle chains -> overlap via ILP.
    #pragma unroll
    for (int off = 32; off > 0; off >>= 1) {
        #pragma unroll
        for (int r = 0; r < RPW; ++r) {
            dot[r] += __shfl_down(dot[r], off, 64);
            aa[r]  += __shfl_down(aa[r],  off, 64);
            bb[r]  += __shfl_down(bb[r],  off, 64);
        }
    }

    __shared__ float s_loss[BLOCK / 64];
    if (lane == 0) {
        float loss = 0.f;
        #pragma unroll
        for (int r = 0; r < RPW; ++r)
            loss += 1.0f - dot[r] * rsqrtf(aa[r] * bb[r]);
        s_loss[wave] = loss;
    }
    __syncthreads();
    if (threadIdx.x == 0) {
        partial[blockIdx.x] = s_loss[0] + s_loss[1] + s_loss[2] + s_loss[3];
    }
}

__global__ __launch_bounds__(BLOCK) void cosine_reduce_kernel(
    const float* __restrict__ partial,
    float* __restrict__ out) {
    float s = 0.f;
    for (int i = threadIdx.x; i < GRID; i += BLOCK) s += partial[i];
    #pragma unroll
    for (int off = 32; off > 0; off >>= 1) s += __shfl_down(s, off, 64);

    __shared__ float s_sum[BLOCK / 64];
    const int wave = threadIdx.x >> 6;
    const int lane = threadIdx.x & 63;
    if (lane == 0) s_sum[wave] = s;
    __syncthreads();
    if (threadIdx.x == 0) {
        out[0] = (s_sum[0] + s_sum[1] + s_sum[2] + s_sum[3]) * (1.0f / (float)ROWS);
    }
}

extern "C" void kernel_launch(void* const* d_in, const int* in_sizes, int n_in,
                              void* d_out, int out_size, void* d_ws, size_t ws_size,
                              hipStream_t stream) {
    const float4* cxr = (const float4*)d_in[0];
    const float4* ehr = (const float4*)d_in[1];
    float* out     = (float*)d_out;
    float* partial = (float*)d_ws;  // GRID floats = 4 KB, fully overwritten

    cosine_partial_kernel<<<GRID, BLOCK, 0, stream>>>(cxr, ehr, partial);
    cosine_reduce_kernel<<<1, BLOCK, 0, stream>>>(partial, out);
}

// Round 4
// 275.255 us; speedup vs baseline: 1.0480x; 1.0480x over previous
//
#include <hip/hip_runtime.h>
#include <hip/hip_bf16.h>

// CosineLoss: out = mean_i( 1 - dot(a_i,b_i) / (||a_i||*||b_i||) )
// inputs: d_in[0]=cxr (N,D) f32, d_in[1]=ehr (N,D) f32; N=16384, D=2048.
//
// R3 lesson: explicit double-buffer arrays spilled to scratch (WRITE_SIZE
// 38 MB) -> regression. R2/R3 both plateaued at ~2.7 TB/s delivered because
// 8192 independent per-wave streams scatter the in-flight address window
// over the whole 268 MB (DRAM page thrash). Now: BabelStream-style compact
// sliding window — one 512-thread block covers one FULL row per step, all
// 512 blocks in lockstep read a contiguous 4 MB window per array that
// slides sequentially. Wave-shuffle per-step reduce, LDS wave-partials,
// ONE barrier per block at the end.

#define ROWS 16384
#define COLS_V4 512               // float4 per row (D=2048)
#define BLOCK 512                 // 8 waves; 512 lanes x vec4 = one full row
#define GRID 512                  // 2 blocks/CU, all resident
#define STEPS (ROWS / GRID)       // 32 rows per block
#define WPB (BLOCK / 64)          // 8 waves per block

__global__ __launch_bounds__(BLOCK, 2) void cosine_partial_kernel(
    const float4* __restrict__ A,
    const float4* __restrict__ B,
    float* __restrict__ partial) {
    const int t    = threadIdx.x;
    const int wave = t >> 6;
    const int lane = t & 63;

    // s_part[s][w] = {dot, aa, bb} wave-partial for row (s*GRID + blockIdx.x)
    __shared__ float s_part[STEPS][WPB][3];   // 3 KB

    // vec4 index at step s: (s*GRID + blockIdx.x)*COLS_V4 + t
    const float4* __restrict__ a = A + (size_t)blockIdx.x * COLS_V4 + t;
    const float4* __restrict__ b = B + (size_t)blockIdx.x * COLS_V4 + t;
    const size_t stride = (size_t)GRID * COLS_V4;   // vec4 per step

    // software pipeline: next step's 2 loads in flight during current compute
    float4 x = a[0];
    float4 y = b[0];
    for (int s = 0; s < STEPS; ++s) {
        float4 xn, yn;
        if (s + 1 < STEPS) {
            xn = a[(size_t)(s + 1) * stride];
            yn = b[(size_t)(s + 1) * stride];
        }
        float d  = x.x * y.x + x.y * y.y + x.z * y.z + x.w * y.w;
        float na = x.x * x.x + x.y * x.y + x.z * x.z + x.w * x.w;
        float nb = y.x * y.x + y.y * y.y + y.z * y.z + y.w * y.w;
        #pragma unroll
        for (int off = 32; off > 0; off >>= 1) {
            d  += __shfl_down(d,  off, 64);
            na += __shfl_down(na, off, 64);
            nb += __shfl_down(nb, off, 64);
        }
        if (lane == 0) {
            s_part[s][wave][0] = d;
            s_part[s][wave][1] = na;
            s_part[s][wave][2] = nb;
        }
        x = xn;
        y = yn;
    }
    __syncthreads();

    // threads 0..STEPS-1 (all in wave 0, STEPS=32<=64) each finish one row
    float loss = 0.f;
    if (t < STEPS) {
        float d = 0.f, na = 0.f, nb = 0.f;
        #pragma unroll
        for (int w = 0; w < WPB; ++w) {
            d  += s_part[t][w][0];
            na += s_part[t][w][1];
            nb += s_part[t][w][2];
        }
        loss = 1.0f - d * rsqrtf(na * nb);
    }
    if (wave == 0) {
        #pragma unroll
        for (int off = 16; off > 0; off >>= 1)
            loss += __shfl_down(loss, off, 64);   // lanes >=32 contribute 0
        if (lane == 0) partial[blockIdx.x] = loss;
    }
}

__global__ __launch_bounds__(256) void cosine_reduce_kernel(
    const float* __restrict__ partial,
    float* __restrict__ out) {
    const int t = threadIdx.x;
    float s = partial[t] + partial[t + 256];   // GRID = 512 = 2*256
    #pragma unroll
    for (int off = 32; off > 0; off >>= 1) s += __shfl_down(s, off, 64);

    __shared__ float s_sum[4];
    const int wave = t >> 6;
    const int lane = t & 63;
    if (lane == 0) s_sum[wave] = s;
    __syncthreads();
    if (t == 0) {
        out[0] = (s_sum[0] + s_sum[1] + s_sum[2] + s_sum[3]) * (1.0f / (float)ROWS);
    }
}

extern "C" void kernel_launch(void* const* d_in, const int* in_sizes, int n_in,
                              void* d_out, int out_size, void* d_ws, size_t ws_size,
                              hipStream_t stream) {
    const float4* cxr = (const float4*)d_in[0];
    const float4* ehr = (const float4*)d_in[1];
    float* out     = (float*)d_out;
    float* partial = (float*)d_ws;   // GRID floats = 2 KB, fully overwritten

    cosine_partial_kernel<<<GRID, BLOCK, 0, stream>>>(cxr, ehr, partial);
    cosine_reduce_kernel<<<1, 256, 0, stream>>>(partial, out);
}